// Round 22
// baseline (102.973 us; speedup 1.0000x reference)
//
#include <hip/hip_runtime.h>

#define B 128
#define N 65536
#define D 512
#define K 5
#define M 256              // D * RATIO
#define GPB 256            // gallery rows per block (kernel1)
#define NBLK1 (N / GPB)    // 256 blocks
#define CHR 16             // g-rows per chunk (full D each)
#define NCHK (GPB / CHR)   // 16

typedef __attribute__((ext_vector_type(8))) short short8;
typedef __attribute__((ext_vector_type(4))) float f32x4;
typedef __attribute__((address_space(1))) const unsigned char as1cu8;
typedef __attribute__((address_space(3))) unsigned char as3u8;

// pack two fp32 -> one u32 of 2 bf16 (truncation) via v_perm_b32.
__device__ __forceinline__ unsigned int pack_bf2(float lo, float hi) {
    return __builtin_amdgcn_perm(__float_as_uint(hi), __float_as_uint(lo), 0x07060302u);
}

__device__ __forceinline__ void top5_insert(float v, int gi, float tv[K], int ti[K]) {
    // descending by value, ties broken by lower index (matches lax.top_k)
    if (v > tv[K - 1] || (v == tv[K - 1] && gi < ti[K - 1])) {
        tv[K - 1] = v; ti[K - 1] = gi;
        #pragma unroll
        for (int k = K - 1; k > 0; --k) {
            bool sw = (tv[k] > tv[k - 1]) || (tv[k] == tv[k - 1] && ti[k] < ti[k - 1]);
            if (sw) {
                float fv = tv[k]; tv[k] = tv[k - 1]; tv[k - 1] = fv;
                int fi = ti[k]; ti[k] = ti[k - 1]; ti[k - 1] = fi;
            }
        }
    }
}

// packed-score insert (meta lives in low 8 mantissa bits; candidates distinct)
__device__ __forceinline__ void pk_insert(float sp, float lst[K]) {
    if (sp > lst[K - 1]) {
        lst[K - 1] = sp;
        #pragma unroll
        for (int k = K - 1; k > 0; --k)
            if (lst[k] > lst[k - 1]) {
                float t2 = lst[k]; lst[k] = lst[k - 1]; lst[k - 1] = t2;
            }
    }
}

// k1 (R22): R18's structure + counted-vmcnt pipeline at 114.8KB LDS.
// R15/R16's counted-vmcnt "failures" were confounded: both had >128KB LDS
// (133-134KB) — suspected allocation cliff. This version keeps the ring
// under 128KB: gbuf 3-deep (96KB), cbuf_c kh0-only (16KB; kh1 carries its
// prev-chunk acc/nrm in registers). Per chunk: vmcnt(2)+lgkmcnt(0) + raw
// s_barrier (chunk c+1's DMA stays in flight), DMA(c+2) post-barrier
// (ring-WAR safe), FINISH(c-1), COMPUTE(c).
__global__ __launch_bounds__(1024) void k1_sims(const float* __restrict__ t_f,
                                                const float* __restrict__ gal,
                                                float2* __restrict__ partial) {
    __shared__ __align__(16) char gbuf[3][CHR * 2048];   // 98304 B ring
    __shared__ __align__(16) float cbuf_c[2][8][256];    // 16384 B kh0 C partials
    __shared__ __align__(16) float cbuf_n[2][16];        //   128 B kh0 row norms

    const int tid = threadIdx.x;
    const int blk = blockIdx.x;
    const int lane = tid & 63;
    const int w = tid >> 6;
    const int l15 = lane & 15;
    const int l4 = lane >> 4;
    const int bt = w & 7;     // b-tile (16 b-rows)
    const int kh = w >> 3;    // k-half (ks 0-7 / 8-15)

    const char* gal_b = reinterpret_cast<const char*>(gal);
    const size_t rowbase = ((size_t)blk * GPB) * (D * 4);
    const int lsw = (lane * 16) ^ ((w & 7) << 4);   // swizzled lane offset (row = w)

    // t-fragments FIRST (so the loop's vmcnt counting is exact):
    // lane holds t[bt*16 + l15][ks*32 + l4*8 .. +8], ks = kh*8+j
    short8 tfr[8];
    {
        const float* tp = t_f + (size_t)(bt * 16 + l15) * D + (kh * 8) * 32 + l4 * 8;
        #pragma unroll
        for (int j = 0; j < 8; ++j) {
            float4 a = *reinterpret_cast<const float4*>(tp + j * 32);
            float4 b = *reinterpret_cast<const float4*>(tp + j * 32 + 4);
            uint4 q;
            q.x = pack_bf2(a.x, a.y); q.y = pack_bf2(a.z, a.w);
            q.z = pack_bf2(b.x, b.y); q.w = pack_bf2(b.z, b.w);
            tfr[j] = *reinterpret_cast<short8*>(&q);
        }
    }
    __builtin_amdgcn_sched_barrier(0);

    // DMA chunk c: wave w stages row w (2KB = 2 insts), swizzled source
#define DMA(c) do { \
        const char* s_ = gal_b + rowbase + ((size_t)(c) * CHR + w) * (D * 4) + lsw; \
        char* d_ = &gbuf[(c) % 3][w * 2048]; \
        __builtin_amdgcn_global_load_lds((as1cu8*)s_, (as3u8*)d_, 16, 0, 0); \
        __builtin_amdgcn_global_load_lds((as1cu8*)(s_ + 1024), (as3u8*)(d_ + 1024), 16, 0, 0); \
    } while (0)

    DMA(0); DMA(1);   // 4 ops/wave in flight

    float lst[K];
    #pragma unroll
    for (int k = 0; k < K; ++k) lst[k] = -1e30f;

    f32x4 accPrev = (f32x4)0.0f;
    float nrmPrev = 0.0f;
    const int xr = (l15 & 7) << 4;

    // COMPUTE chunk c: MFMA over this wave's k-half; kh0 -> cbuf, kh1 -> regs
#define COMPUTE(c) do { \
        f32x4 acc_ = (f32x4)0.0f; \
        float nrm_ = 0.0f; \
        const char* gb_ = &gbuf[(c) % 3][0]; \
        _Pragma("unroll") \
        for (int j_ = 0; j_ < 8; ++j_) { \
            const int ks_ = kh * 8 + j_; \
            const int base_ = l15 * 2048 + ks_ * 128; \
            float4 a0_ = *reinterpret_cast<const float4*>(gb_ + base_ + ((l4 * 32) ^ xr)); \
            float4 a1_ = *reinterpret_cast<const float4*>(gb_ + base_ + ((l4 * 32 + 16) ^ xr)); \
            nrm_ = fmaf(a0_.x, a0_.x, nrm_); nrm_ = fmaf(a0_.y, a0_.y, nrm_); \
            nrm_ = fmaf(a0_.z, a0_.z, nrm_); nrm_ = fmaf(a0_.w, a0_.w, nrm_); \
            nrm_ = fmaf(a1_.x, a1_.x, nrm_); nrm_ = fmaf(a1_.y, a1_.y, nrm_); \
            nrm_ = fmaf(a1_.z, a1_.z, nrm_); nrm_ = fmaf(a1_.w, a1_.w, nrm_); \
            uint4 q_; \
            q_.x = pack_bf2(a0_.x, a0_.y); q_.y = pack_bf2(a0_.z, a0_.w); \
            q_.z = pack_bf2(a1_.x, a1_.y); q_.w = pack_bf2(a1_.z, a1_.w); \
            short8 af_ = *reinterpret_cast<short8*>(&q_); \
            acc_ = __builtin_amdgcn_mfma_f32_16x16x32_bf16(af_, tfr[j_], acc_, 0, 0, 0); \
        } \
        nrm_ += __shfl_xor(nrm_, 16); \
        nrm_ += __shfl_xor(nrm_, 32); \
        if (kh == 0) { \
            *reinterpret_cast<f32x4*>(&cbuf_c[(c) & 1][bt][lane * 4]) = acc_; \
            if (w == 0 && lane < CHR) cbuf_n[(c) & 1][lane] = nrm_; \
        } else { \
            accPrev = acc_; \
            nrmPrev = nrm_; \
        } \
    } while (0)

    // FINISH chunk c (kh1 waves): kh0 halves from cbuf, own halves from regs
#define FINISH(c) do { \
        const int pb_ = (c) & 1; \
        f32x4 c0_ = *reinterpret_cast<const f32x4*>(&cbuf_c[pb_][bt][lane * 4]); \
        float4 n0_ = *reinterpret_cast<const float4*>(&cbuf_n[pb_][l4 * 4]); \
        _Pragma("unroll") \
        for (int r_ = 0; r_ < 4; ++r_) { \
            float nown_ = __shfl(nrmPrev, l4 * 4 + r_); \
            float s_ = (c0_[r_] + accPrev[r_]) * rsqrtf(fmaxf(n0_[r_] + nown_, 1e-24f)); \
            unsigned meta_ = (unsigned)((c) * CHR + l4 * 4 + r_); \
            float sp_ = __uint_as_float((__float_as_uint(s_) & 0xFFFFFF00u) | meta_); \
            pk_insert(sp_, lst); \
        } \
    } while (0)

    // one counted wait + one raw barrier per chunk; DMA(c+2) post-barrier is
    // WAR-safe (slot (c+2)%3 last read at iter c-1; every wave passed this
    // barrier only after finishing those reads).
#define ITER(c, vmn) \
    asm volatile("s_waitcnt vmcnt(" #vmn ") lgkmcnt(0)" ::: "memory"); \
    __builtin_amdgcn_sched_barrier(0); \
    __builtin_amdgcn_s_barrier(); \
    __builtin_amdgcn_sched_barrier(0); \
    if ((c) + 2 < NCHK) DMA((c) + 2); \
    if ((c) > 0 && kh == 1) FINISH((c) - 1); \
    COMPUTE(c);

    ITER(0, 2)  ITER(1, 2)  ITER(2, 2)  ITER(3, 2)
    ITER(4, 2)  ITER(5, 2)  ITER(6, 2)  ITER(7, 2)
    ITER(8, 2)  ITER(9, 2)  ITER(10, 2) ITER(11, 2)
    ITER(12, 2) ITER(13, 2) ITER(14, 2) ITER(15, 0)

    // drain chunk 15's cbuf writes, then final finish
    asm volatile("s_waitcnt lgkmcnt(0)" ::: "memory");
    __builtin_amdgcn_sched_barrier(0);
    __builtin_amdgcn_s_barrier();
    __builtin_amdgcn_sched_barrier(0);

    if (kh == 1) {
        FINISH(NCHK - 1);
        // merge per-b lists across the 4 l4 lanes (same b = bt*16 + l15)
        #pragma unroll
        for (int mk = 16; mk <= 32; mk <<= 1) {
            float inc[K];
            #pragma unroll
            for (int k = 0; k < K; ++k) inc[k] = __shfl_xor(lst[k], mk);
            #pragma unroll
            for (int k = 0; k < K; ++k) pk_insert(inc[k], lst);
        }
        if (l4 == 0) {
            const int b = bt * 16 + l15;
            #pragma unroll
            for (int k = 0; k < K; ++k) {
                unsigned sp = __float_as_uint(lst[k]);
                int g = blk * GPB + (int)(sp & 0xFFu);
                partial[((size_t)b * NBLK1 + blk) * K + k] = make_float2(lst[k], __int_as_float(g));
            }
        }
    }
#undef ITER
#undef FINISH
#undef COMPUTE
#undef DMA
}

// k2: merge 256 partial top-5 lists per batch row -> top_idx. Shuffle-first.
__global__ __launch_bounds__(512) void k2_merge(const float2* __restrict__ partial,
                                                int* __restrict__ top_idx) {
    __shared__ float2 wlist[8][K];
    const int b = blockIdx.x;
    const int p = threadIdx.x;
    const int lane = p & 63;
    const int w = p >> 6;

    float mv[K]; int mi[K];
    #pragma unroll
    for (int k = 0; k < K; ++k) { mv[k] = -1e30f; mi[k] = 0x7fffffff; }
    if (p < NBLK1) {
        #pragma unroll
        for (int k = 0; k < K; ++k) {
            float2 c = partial[((size_t)b * NBLK1 + p) * K + k];
            mv[k] = c.x; mi[k] = __float_as_int(c.y);
        }
    }
    #pragma unroll
    for (int mk = 1; mk <= 32; mk <<= 1) {
        float ov[K]; int oi[K];
        #pragma unroll
        for (int k = 0; k < K; ++k) { ov[k] = __shfl_xor(mv[k], mk); oi[k] = __shfl_xor(mi[k], mk); }
        #pragma unroll
        for (int k = 0; k < K; ++k) top5_insert(ov[k], oi[k], mv, mi);
    }
    if (lane == 0) {
        #pragma unroll
        for (int k = 0; k < K; ++k) wlist[w][k] = make_float2(mv[k], __int_as_float(mi[k]));
    }
    __syncthreads();
    if (w == 0) {
        #pragma unroll
        for (int k = 0; k < K; ++k) { mv[k] = -1e30f; mi[k] = 0x7fffffff; }
        if (lane < 8) {
            #pragma unroll
            for (int k = 0; k < K; ++k) {
                float2 c = wlist[lane][k];
                mv[k] = c.x; mi[k] = __float_as_int(c.y);
            }
        }
        #pragma unroll
        for (int mk = 1; mk <= 4; mk <<= 1) {
            float ov[K]; int oi[K];
            #pragma unroll
            for (int k = 0; k < K; ++k) { ov[k] = __shfl_xor(mv[k], mk); oi[k] = __shfl_xor(mi[k], mk); }
            #pragma unroll
            for (int k = 0; k < K; ++k) top5_insert(ov[k], oi[k], mv, mi);
        }
        if (lane == 0) {
            #pragma unroll
            for (int k = 0; k < K; ++k) top_idx[b * K + k] = mi[k];
        }
    }
}

// k3: one block per (b,k) row: bottom-m membership of |gal[row,c]*s_f[b,c]|
// (per-row norms are positive constants -> ordering matches the reference's
// normalized products). Plain stores; kernel-boundary coherence (R8 lesson).
__global__ __launch_bounds__(512) void k3_member(const float* __restrict__ s_f,
                                                 const float* __restrict__ gal,
                                                 const int* __restrict__ top_idx,
                                                 unsigned long long* __restrict__ bkmask) {
    __shared__ __align__(16) float pS[D];
    const int p = threadIdx.x;
    const int bk = blockIdx.x;
    const int b = bk / K;
    const int row = top_idx[bk];
    float pv = fabsf(gal[(size_t)row * D + p] * s_f[(size_t)b * D + p]);
    pS[p] = pv;
    __syncthreads();
    int cnt = 0;
    const float4* p4 = reinterpret_cast<const float4*>(pS);
    #pragma unroll 4
    for (int j = 0; j < D / 4; ++j) {
        float4 o = p4[j];
        cnt += (o.x < pv || (o.x == pv && (4 * j + 0) < p)) ? 1 : 0;
        cnt += (o.y < pv || (o.y == pv && (4 * j + 1) < p)) ? 1 : 0;
        cnt += (o.z < pv || (o.z == pv && (4 * j + 2) < p)) ? 1 : 0;
        cnt += (o.w < pv || (o.w == pv && (4 * j + 3) < p)) ? 1 : 0;
    }
    unsigned long long bm = __ballot(cnt < M);
    if ((p & 63) == 0) bkmask[(size_t)bk * 8 + (p >> 6)] = bm;
}

// k4: parallel AND-reduce of the 640 per-(b,k) masks.
__global__ __launch_bounds__(512) void k4_final(const unsigned long long* __restrict__ bkmask,
                                                float* __restrict__ out) {
    __shared__ unsigned long long red[64][8];
    const int t = threadIdx.x;
    {
        const int word = t & 7, seg = t >> 3;   // seg 0..63
        unsigned long long acc = ~0ull;
        #pragma unroll
        for (int i = 0; i < 10; ++i)
            acc &= bkmask[(size_t)(seg * 10 + i) * 8 + word];
        red[seg][word] = acc;
    }
    __syncthreads();
    const int word = t >> 6, bit = t & 63;
    unsigned long long m = ~0ull;
    #pragma unroll 8
    for (int seg = 0; seg < 64; ++seg) m &= red[seg][word];
    out[t] = ((m >> bit) & 1ull) ? 0.0f : 1.0f;
}

extern "C" void kernel_launch(void* const* d_in, const int* in_sizes, int n_in,
                              void* d_out, int out_size, void* d_ws, size_t ws_size,
                              hipStream_t stream) {
    (void)in_sizes; (void)n_in; (void)out_size; (void)ws_size;
    const float* s_f = (const float*)d_in[0];
    const float* t_f = (const float*)d_in[1];
    const float* gal = (const float*)d_in[2];
    float* out = (float*)d_out;

    char* ws = (char*)d_ws;
    const size_t off_partial = 0;                        // 128*256*5*8 = 1310720
    const size_t off_topidx  = off_partial + 1310720;    // 2560
    const size_t off_bkmask  = off_topidx + 2560;        // 40960

    float2* partial = (float2*)(ws + off_partial);
    int* top_idx = (int*)(ws + off_topidx);
    unsigned long long* bkmask = (unsigned long long*)(ws + off_bkmask);

    hipLaunchKernelGGL(k1_sims, dim3(NBLK1), dim3(1024), 0, stream, t_f, gal, partial);
    hipLaunchKernelGGL(k2_merge, dim3(B), dim3(512), 0, stream, partial, top_idx);
    hipLaunchKernelGGL(k3_member, dim3(B * K), dim3(512), 0, stream, s_f, gal, top_idx, bkmask);
    hipLaunchKernelGGL(k4_final, dim3(1), dim3(512), 0, stream, bkmask, out);
}

// Round 23
// 91.245 us; speedup vs baseline: 1.1285x; 1.1285x over previous
//
#include <hip/hip_runtime.h>

#define B 128
#define N 65536
#define D 512
#define K 5
#define M 256              // D * RATIO
#define GPB 256            // gallery rows per block (kernel1)
#define NBLK1 (N / GPB)    // 256 blocks
#define CHR 16             // g-rows per chunk (full D each)
#define NCHK (GPB / CHR)   // 16

typedef __attribute__((ext_vector_type(8))) short short8;
typedef __attribute__((ext_vector_type(4))) float f32x4;
typedef __attribute__((address_space(1))) const unsigned char as1cu8;
typedef __attribute__((address_space(3))) unsigned char as3u8;

// pack two fp32 -> one u32 of 2 bf16 (truncation) via v_perm_b32.
__device__ __forceinline__ unsigned int pack_bf2(float lo, float hi) {
    return __builtin_amdgcn_perm(__float_as_uint(hi), __float_as_uint(lo), 0x07060302u);
}

__device__ __forceinline__ void top5_insert(float v, int gi, float tv[K], int ti[K]) {
    // descending by value, ties broken by lower index (matches lax.top_k)
    if (v > tv[K - 1] || (v == tv[K - 1] && gi < ti[K - 1])) {
        tv[K - 1] = v; ti[K - 1] = gi;
        #pragma unroll
        for (int k = K - 1; k > 0; --k) {
            bool sw = (tv[k] > tv[k - 1]) || (tv[k] == tv[k - 1] && ti[k] < ti[k - 1]);
            if (sw) {
                float fv = tv[k]; tv[k] = tv[k - 1]; tv[k - 1] = fv;
                int fi = ti[k]; ti[k] = ti[k - 1]; ti[k - 1] = fi;
            }
        }
    }
}

// packed-score insert (meta lives in low 8 mantissa bits; candidates distinct)
__device__ __forceinline__ void pk_insert(float sp, float lst[K]) {
    if (sp > lst[K - 1]) {
        lst[K - 1] = sp;
        #pragma unroll
        for (int k = K - 1; k > 0; --k)
            if (lst[k] > lst[k - 1]) {
                float t2 = lst[k]; lst[k] = lst[k - 1]; lst[k - 1] = t2;
            }
    }
}

// k1 (R18 configuration — session best, 91.5us total; reproduced R21 91.6us):
// fp32 gallery via global_load_lds, 16 waves = (bt 0..7) x (kh 0..1),
// t-fragments 32 regs/wave, single __syncthreads per chunk, cross-k-half C
// exchange one chunk behind. Verified against alternatives: counted-vmcnt
// slower (R15/R16/R22), 2-blocks/CU impossible for 1024-thr WGs (R20),
// reg-staging slower (R17), 8-wave variants slower (R13).
__global__ __launch_bounds__(1024) void k1_sims(const float* __restrict__ t_f,
                                                const float* __restrict__ gal,
                                                float2* __restrict__ partial) {
    __shared__ __align__(16) char gbuf[2][CHR * 2048];   // 65536 B fp32 chunks
    __shared__ __align__(16) float cbuf_c[2][16][256];   // 32768 B C exchange
    __shared__ __align__(16) float cbuf_n[2][16][16];    //  2048 B norm exchange

    const int tid = threadIdx.x;
    const int blk = blockIdx.x;
    const int lane = tid & 63;
    const int w = tid >> 6;
    const int l15 = lane & 15;
    const int l4 = lane >> 4;
    const int bt = w & 7;     // b-tile (16 b-rows)
    const int kh = w >> 3;    // k-half (ks 0-7 / 8-15)

    const char* gal_b = reinterpret_cast<const char*>(gal);
    const size_t rowbase = ((size_t)blk * GPB) * (D * 4);
    const int lsw = (lane * 16) ^ ((w & 7) << 4);   // swizzled lane offset (row = w)

    // DMA chunk c into gbuf[bi]: wave w stages row w of the chunk (2KB = 2 insts)
    auto DMA = [&](int c, int bi) {
        const char* s0 = gal_b + rowbase + ((size_t)c * CHR + w) * (D * 4) + lsw;
        char* d = &gbuf[bi][w * 2048];
        __builtin_amdgcn_global_load_lds((as1cu8*)s0, (as3u8*)d, 16, 0, 0);
        __builtin_amdgcn_global_load_lds((as1cu8*)(s0 + 1024), (as3u8*)(d + 1024), 16, 0, 0);
    };

    DMA(0, 0);

    // t-fragments: lane holds t[bt*16 + l15][ks*32 + l4*8 .. +8], ks = kh*8+j
    short8 tfr[8];
    {
        const float* tp = t_f + (size_t)(bt * 16 + l15) * D + (kh * 8) * 32 + l4 * 8;
        #pragma unroll
        for (int j = 0; j < 8; ++j) {
            float4 a = *reinterpret_cast<const float4*>(tp + j * 32);
            float4 b = *reinterpret_cast<const float4*>(tp + j * 32 + 4);
            uint4 q;
            q.x = pack_bf2(a.x, a.y); q.y = pack_bf2(a.z, a.w);
            q.z = pack_bf2(b.x, b.y); q.w = pack_bf2(b.z, b.w);
            tfr[j] = *reinterpret_cast<short8*>(&q);
        }
    }

    float lst[K];
    #pragma unroll
    for (int k = 0; k < K; ++k) lst[k] = -1e30f;

    const int xr = (l15 & 7) << 4;
    __syncthreads();   // chunk 0 staged

    for (int c = 0; c < NCHK; ++c) {
        const int bi = c & 1;
        if (c + 1 < NCHK) DMA(c + 1, bi ^ 1);

        // finish previous chunk: sum k-halves, scale, insert (kh==1 waves)
        if (c > 0 && kh == 1) {
            const int pb = bi ^ 1;
            f32x4 c0 = *reinterpret_cast<const f32x4*>(&cbuf_c[pb][bt][lane * 4]);
            f32x4 c1 = *reinterpret_cast<const f32x4*>(&cbuf_c[pb][8 + bt][lane * 4]);
            float4 n0 = *reinterpret_cast<const float4*>(&cbuf_n[pb][bt][l4 * 4]);
            float4 n1 = *reinterpret_cast<const float4*>(&cbuf_n[pb][8 + bt][l4 * 4]);
            float nn[4] = {n0.x + n1.x, n0.y + n1.y, n0.z + n1.z, n0.w + n1.w};
            #pragma unroll
            for (int r = 0; r < 4; ++r) {
                float s = (c0[r] + c1[r]) * rsqrtf(fmaxf(nn[r], 1e-24f));
                unsigned meta = (unsigned)((c - 1) * CHR + l4 * 4 + r);
                float sp = __uint_as_float((__float_as_uint(s) & 0xFFFFFF00u) | meta);
                pk_insert(sp, lst);
            }
        }

        // compute chunk c: 8 k-slices (this wave's k-half)
        f32x4 acc = (f32x4)0.0f;
        float nrm = 0.0f;
        const char* gb = &gbuf[bi][0];
        #pragma unroll
        for (int j = 0; j < 8; ++j) {
            const int ks = kh * 8 + j;
            const int base = l15 * 2048 + ks * 128;
            float4 a0 = *reinterpret_cast<const float4*>(gb + base + ((l4 * 32) ^ xr));
            float4 a1 = *reinterpret_cast<const float4*>(gb + base + ((l4 * 32 + 16) ^ xr));
            nrm = fmaf(a0.x, a0.x, nrm); nrm = fmaf(a0.y, a0.y, nrm);
            nrm = fmaf(a0.z, a0.z, nrm); nrm = fmaf(a0.w, a0.w, nrm);
            nrm = fmaf(a1.x, a1.x, nrm); nrm = fmaf(a1.y, a1.y, nrm);
            nrm = fmaf(a1.z, a1.z, nrm); nrm = fmaf(a1.w, a1.w, nrm);
            uint4 q;
            q.x = pack_bf2(a0.x, a0.y); q.y = pack_bf2(a0.z, a0.w);
            q.z = pack_bf2(a1.x, a1.y); q.w = pack_bf2(a1.z, a1.w);
            short8 af = *reinterpret_cast<short8*>(&q);
            acc = __builtin_amdgcn_mfma_f32_16x16x32_bf16(af, tfr[j], acc, 0, 0, 0);
        }
        // half-row norms: sum over l4 quarters (this k-half)
        nrm += __shfl_xor(nrm, 16);
        nrm += __shfl_xor(nrm, 32);
        if (lane < CHR) cbuf_n[bi][w][lane] = nrm;
        *reinterpret_cast<f32x4*>(&cbuf_c[bi][w][lane * 4]) = acc;

        __syncthreads();   // cbuf visible + next chunk's DMA drained
    }

    // epilogue: finish chunk NCHK-1
    if (kh == 1) {
        const int pb = (NCHK - 1) & 1;
        f32x4 c0 = *reinterpret_cast<const f32x4*>(&cbuf_c[pb][bt][lane * 4]);
        f32x4 c1 = *reinterpret_cast<const f32x4*>(&cbuf_c[pb][8 + bt][lane * 4]);
        float4 n0 = *reinterpret_cast<const float4*>(&cbuf_n[pb][bt][l4 * 4]);
        float4 n1 = *reinterpret_cast<const float4*>(&cbuf_n[pb][8 + bt][l4 * 4]);
        float nn[4] = {n0.x + n1.x, n0.y + n1.y, n0.z + n1.z, n0.w + n1.w};
        #pragma unroll
        for (int r = 0; r < 4; ++r) {
            float s = (c0[r] + c1[r]) * rsqrtf(fmaxf(nn[r], 1e-24f));
            unsigned meta = (unsigned)((NCHK - 1) * CHR + l4 * 4 + r);
            float sp = __uint_as_float((__float_as_uint(s) & 0xFFFFFF00u) | meta);
            pk_insert(sp, lst);
        }
    }

    // merge per-b lists across the 4 l4 lanes (masks 16, 32)
    #pragma unroll
    for (int mk = 16; mk <= 32; mk <<= 1) {
        float inc[K];
        #pragma unroll
        for (int k = 0; k < K; ++k) inc[k] = __shfl_xor(lst[k], mk);
        #pragma unroll
        for (int k = 0; k < K; ++k) pk_insert(inc[k], lst);
    }

    if (kh == 1 && l4 == 0) {
        const int b = bt * 16 + l15;
        #pragma unroll
        for (int k = 0; k < K; ++k) {
            unsigned sp = __float_as_uint(lst[k]);
            int g = blk * GPB + (int)(sp & 0xFFu);
            partial[((size_t)b * NBLK1 + blk) * K + k] = make_float2(lst[k], __int_as_float(g));
        }
    }
}

// k2: merge 256 partial top-5 lists per batch row -> top_idx. Shuffle-first.
__global__ __launch_bounds__(512) void k2_merge(const float2* __restrict__ partial,
                                                int* __restrict__ top_idx) {
    __shared__ float2 wlist[8][K];
    const int b = blockIdx.x;
    const int p = threadIdx.x;
    const int lane = p & 63;
    const int w = p >> 6;

    float mv[K]; int mi[K];
    #pragma unroll
    for (int k = 0; k < K; ++k) { mv[k] = -1e30f; mi[k] = 0x7fffffff; }
    if (p < NBLK1) {
        #pragma unroll
        for (int k = 0; k < K; ++k) {
            float2 c = partial[((size_t)b * NBLK1 + p) * K + k];
            mv[k] = c.x; mi[k] = __float_as_int(c.y);
        }
    }
    #pragma unroll
    for (int mk = 1; mk <= 32; mk <<= 1) {
        float ov[K]; int oi[K];
        #pragma unroll
        for (int k = 0; k < K; ++k) { ov[k] = __shfl_xor(mv[k], mk); oi[k] = __shfl_xor(mi[k], mk); }
        #pragma unroll
        for (int k = 0; k < K; ++k) top5_insert(ov[k], oi[k], mv, mi);
    }
    if (lane == 0) {
        #pragma unroll
        for (int k = 0; k < K; ++k) wlist[w][k] = make_float2(mv[k], __int_as_float(mi[k]));
    }
    __syncthreads();
    if (w == 0) {
        #pragma unroll
        for (int k = 0; k < K; ++k) { mv[k] = -1e30f; mi[k] = 0x7fffffff; }
        if (lane < 8) {
            #pragma unroll
            for (int k = 0; k < K; ++k) {
                float2 c = wlist[lane][k];
                mv[k] = c.x; mi[k] = __float_as_int(c.y);
            }
        }
        #pragma unroll
        for (int mk = 1; mk <= 4; mk <<= 1) {
            float ov[K]; int oi[K];
            #pragma unroll
            for (int k = 0; k < K; ++k) { ov[k] = __shfl_xor(mv[k], mk); oi[k] = __shfl_xor(mi[k], mk); }
            #pragma unroll
            for (int k = 0; k < K; ++k) top5_insert(ov[k], oi[k], mv, mi);
        }
        if (lane == 0) {
            #pragma unroll
            for (int k = 0; k < K; ++k) top_idx[b * K + k] = mi[k];
        }
    }
}

// k3: one block per (b,k) row: bottom-m membership of |gal[row,c]*s_f[b,c]|
// (per-row norms are positive constants -> ordering matches the reference's
// normalized products). Plain stores; kernel-boundary coherence (R8 lesson).
__global__ __launch_bounds__(512) void k3_member(const float* __restrict__ s_f,
                                                 const float* __restrict__ gal,
                                                 const int* __restrict__ top_idx,
                                                 unsigned long long* __restrict__ bkmask) {
    __shared__ __align__(16) float pS[D];
    const int p = threadIdx.x;
    const int bk = blockIdx.x;
    const int b = bk / K;
    const int row = top_idx[bk];
    float pv = fabsf(gal[(size_t)row * D + p] * s_f[(size_t)b * D + p]);
    pS[p] = pv;
    __syncthreads();
    int cnt = 0;
    const float4* p4 = reinterpret_cast<const float4*>(pS);
    #pragma unroll 4
    for (int j = 0; j < D / 4; ++j) {
        float4 o = p4[j];
        cnt += (o.x < pv || (o.x == pv && (4 * j + 0) < p)) ? 1 : 0;
        cnt += (o.y < pv || (o.y == pv && (4 * j + 1) < p)) ? 1 : 0;
        cnt += (o.z < pv || (o.z == pv && (4 * j + 2) < p)) ? 1 : 0;
        cnt += (o.w < pv || (o.w == pv && (4 * j + 3) < p)) ? 1 : 0;
    }
    unsigned long long bm = __ballot(cnt < M);
    if ((p & 63) == 0) bkmask[(size_t)bk * 8 + (p >> 6)] = bm;
}

// k4: parallel AND-reduce of the 640 per-(b,k) masks (R18's win: -34us vs
// the serial single-block scan).
__global__ __launch_bounds__(512) void k4_final(const unsigned long long* __restrict__ bkmask,
                                                float* __restrict__ out) {
    __shared__ unsigned long long red[64][8];
    const int t = threadIdx.x;
    {
        const int word = t & 7, seg = t >> 3;   // seg 0..63
        unsigned long long acc = ~0ull;
        #pragma unroll
        for (int i = 0; i < 10; ++i)
            acc &= bkmask[(size_t)(seg * 10 + i) * 8 + word];
        red[seg][word] = acc;
    }
    __syncthreads();
    const int word = t >> 6, bit = t & 63;
    unsigned long long m = ~0ull;
    #pragma unroll 8
    for (int seg = 0; seg < 64; ++seg) m &= red[seg][word];
    out[t] = ((m >> bit) & 1ull) ? 0.0f : 1.0f;
}

extern "C" void kernel_launch(void* const* d_in, const int* in_sizes, int n_in,
                              void* d_out, int out_size, void* d_ws, size_t ws_size,
                              hipStream_t stream) {
    (void)in_sizes; (void)n_in; (void)out_size; (void)ws_size;
    const float* s_f = (const float*)d_in[0];
    const float* t_f = (const float*)d_in[1];
    const float* gal = (const float*)d_in[2];
    float* out = (float*)d_out;

    char* ws = (char*)d_ws;
    const size_t off_partial = 0;                        // 128*256*5*8 = 1310720
    const size_t off_topidx  = off_partial + 1310720;    // 2560
    const size_t off_bkmask  = off_topidx + 2560;        // 40960

    float2* partial = (float2*)(ws + off_partial);
    int* top_idx = (int*)(ws + off_topidx);
    unsigned long long* bkmask = (unsigned long long*)(ws + off_bkmask);

    hipLaunchKernelGGL(k1_sims, dim3(NBLK1), dim3(1024), 0, stream, t_f, gal, partial);
    hipLaunchKernelGGL(k2_merge, dim3(B), dim3(512), 0, stream, partial, top_idx);
    hipLaunchKernelGGL(k3_member, dim3(B * K), dim3(512), 0, stream, s_f, gal, top_idx, bkmask);
    hipLaunchKernelGGL(k4_final, dim3(1), dim3(512), 0, stream, bkmask, out);
}